// Round 9
// baseline (395.794 us; speedup 1.0000x reference)
//
#include <hip/hip_runtime.h>
#include <hip/hip_bf16.h>
#include <stdint.h>

typedef __bf16 bf16_t;
typedef bf16_t bf16x8 __attribute__((ext_vector_type(8)));
typedef float f32x4 __attribute__((ext_vector_type(4)));

#define T_LEN 2048
#define C_LEN 2048
#define NB 128
#define TN 256
#define SROWS 2064    // 16 zero-halo rows + 2048 data rows per batch
#define XROWS 288     // 9 x 4KB GLL rounds (256 thr); rows 0..271 consumed

// async global->LDS, 16B per lane; LDS dest = wave-uniform base + lane*16
#define GLL(gp, lp) __builtin_amdgcn_global_load_lds( \
    (const __attribute__((address_space(1))) uint32_t*)(gp), \
    (__attribute__((address_space(3))) uint32_t*)(lp), 16, 0, 0)

// ---------------------------------------------------------------------------
// Prepack weights into per-lane MFMA A-fragment layout (verified r1-r8):
// wpk[blk][s(32)][mt(4)][lane(64)][j(8)]
//   = bv[blk][o = mt*16 + (lane&15)][i = (s&1)*32 + (lane>>4)*8 + j][k = s>>1]
// ---------------------------------------------------------------------------
__global__ __launch_bounds__(256) void prepack_kernel(
    const float* __restrict__ bv, bf16_t* __restrict__ wpk)
{
  const int blk = blockIdx.x;
  const int mt  = blockIdx.y;
  const int tid = threadIdx.x;
  __shared__ float lw[16 * 64 * 17];

  const float* src = bv + (size_t)blk * 65536 + (size_t)mt * 16384;
  for (int p = 0; p < 16; ++p) {
    int idx = p * 1024 + tid * 4;
    const float4 v = *(const float4*)(src + idx);
    int o = idx >> 10;
    int i = (idx >> 4) & 63;
    int k = idx & 15;
    float* d = &lw[(o * 64 + i) * 17 + k];
    d[0] = v.x; d[1] = v.y; d[2] = v.z; d[3] = v.w;
  }
  __syncthreads();

  const int e0 = tid * 2;
  const int l  = e0 >> 3;
  const int j  = e0 & 7;
  const int o  = l & 15;
  for (int ks = 0; ks < 32; ++ks) {
    const int k  = ks >> 1;
    const int i0 = (ks & 1) * 32 + (l >> 4) * 8 + j;
    const float a = lw[(o * 64 + i0) * 17 + k];
    const float b = lw[(o * 64 + i0 + 1) * 17 + k];
    const uint16_t ba = __builtin_bit_cast(uint16_t, (bf16_t)a);
    const uint16_t bb = __builtin_bit_cast(uint16_t, (bf16_t)b);
    const uint32_t packed = (uint32_t)ba | ((uint32_t)bb << 16);
    const size_t off = ((((size_t)blk * 32 + ks) * 4 + mt) * 512) + e0;
    *(uint32_t*)(wpk + off) = packed;
  }
}

// ---------------------------------------------------------------------------
// Zero the halo rows of S.
// ---------------------------------------------------------------------------
__global__ __launch_bounds__(256) void padzero_kernel(bf16_t* __restrict__ S)
{
  const int p = blockIdx.x;  // 0..79
  const size_t g = (p < 64) ? ((size_t)(p >> 4) * SROWS + (p & 15))
                            : ((size_t)4 * SROWS + (p - 64));
  uint4 z = {0u, 0u, 0u, 0u};
  *(uint4*)(S + g * C_LEN + (size_t)threadIdx.x * 8) = z;
}

// ---------------------------------------------------------------------------
// x prepass: f32 [n][c][t] -> bf16 S[n][16+t][c'], c' = c ^ ((t&7)<<3)
// within each 64-ch block (XOR swizzle baked into global layout).
// ---------------------------------------------------------------------------
__global__ __launch_bounds__(256) void xprep_kernel(
    const float* __restrict__ x, bf16_t* __restrict__ S)
{
  const int tb = blockIdx.x, cb = blockIdx.y, n = blockIdx.z;
  const int tid = threadIdx.x;
  __shared__ float lt[64 * 67 + 4];

  #pragma unroll
  for (int p = 0; p < 4; ++p) {
    const int idx = p * 256 + tid;
    const int c   = idx >> 4;
    const int t4  = (idx & 15) * 4;
    const float4 v = *(const float4*)(
        x + ((size_t)n * C_LEN + cb * 64 + c) * T_LEN + tb * 64 + t4);
    float* d = &lt[c * 67 + t4];
    d[0] = v.x; d[1] = v.y; d[2] = v.z; d[3] = v.w;
  }
  __syncthreads();

  #pragma unroll
  for (int p = 0; p < 2; ++p) {
    const int idx = p * 256 + tid;
    const int tl  = idx >> 3;
    const int seg = idx & 7;
    const int t   = tb * 64 + tl;
    const int cbase = (seg * 8) ^ ((t & 7) << 3);
    uint32_t w[4];
    #pragma unroll
    for (int h = 0; h < 4; ++h) {
      const float a = lt[(cbase + 2 * h) * 67 + tl];
      const float b = lt[(cbase + 2 * h + 1) * 67 + tl];
      const uint16_t ba = __builtin_bit_cast(uint16_t, (bf16_t)a);
      const uint16_t bb = __builtin_bit_cast(uint16_t, (bf16_t)b);
      w[h] = (uint32_t)ba | ((uint32_t)bb << 16);
    }
    uint4 u4 = {w[0], w[1], w[2], w[3]};
    *(uint4*)(S + ((size_t)n * SROWS + 16 + t) * C_LEN + cb * 64 + seg * 8) = u4;
  }
}

// ---------------------------------------------------------------------------
// Main kernel: 256 thr (4 waves), ~37.5 KB LDS -> 3 WG/CU (12 waves/CU).
// Wave wv: output rows [tr*64,+64) x t-cols [t0+wv*64,+64) (64x64 tile).
// - A (weights): global->VGPR from fragment-layout wpk via a REGISTER
//   ring-4 with 3-s-unit lookahead (~930 cyc >> L3 latency). Only LDS
//   traffic left is B -> LDS-read pipe 82us -> 41us; MFMA (66us) is now
//   the pole. No manual waits: the only vmem in the s-loop is compiler-
//   tracked register loads (correctness model proven in r3).
// - x: single 36.9KB buffer via GLL at the block seam; two __syncthreads
//   (each drains vmcnt to 0) bracket the staging -- nothing is ever in
//   flight across a barrier.
// ---------------------------------------------------------------------------
__global__ __launch_bounds__(256, 3) void bsconv_kernel(
    const bf16_t* __restrict__ S, const bf16_t* __restrict__ wpk,
    const int* __restrict__ cols, const int* __restrict__ rows,
    float* __restrict__ y)
{
  const int tt = blockIdx.x, tr = blockIdx.y, n = blockIdx.z;
  const int t0 = tt * TN;
  const int tid = threadIdx.x;
  const int lane = tid & 63, wv = tid >> 6;   // wv 0..3

  __shared__ __attribute__((aligned(16))) bf16_t xst[XROWS * 64];   // 36864 B
  __shared__ int alist[NB];                   // packed: blk | (col<<8)
  __shared__ unsigned long long wmask[2];

  // ---- build active-block list (order-preserving => deterministic) ----
  {
    const int r  = (tid < NB) ? rows[tid] : -1;
    const int cb = (tid < NB) ? cols[tid] : 0;
    const bool match = (r == tr);
    const unsigned long long m = __ballot(match);
    if (wv < 2 && lane == 0) wmask[wv] = m;
    __syncthreads();
    if (match) {
      int pos = __popcll(wmask[wv] & ((1ull << lane) - 1ull));
      if (wv == 1) pos += __popcll(wmask[0]);
      alist[pos] = tid | (cb << 8);
    }
    __syncthreads();
  }
  const int cnt = __popcll(wmask[0]) + __popcll(wmask[1]);

  f32x4 acc[4][4];
  #pragma unroll
  for (int a = 0; a < 4; ++a)
    #pragma unroll
    for (int b = 0; b < 4; ++b) {
      f32x4 z = {0.f, 0.f, 0.f, 0.f};
      acc[a][b] = z;
    }

  const size_t srow0 = (size_t)n * SROWS + t0;  // S row of LDS row u=0
  const int lxb = tid * 16;                     // lane byte within a 4KB round

  auto issue_x = [&](int cb) {                  // 9 rounds = 36 KB, single buf
    #pragma unroll
    for (int q = 0; q < 9; ++q) {
      const int lb = q * 4096 + lxb;
      const int u  = lb >> 7;                   // LDS row (128 B rows)
      const int ib = (lb >> 1) & 63;
      GLL(S + (srow0 + u) * C_LEN + cb * 64 + ib, (char*)xst + lb);
    }
  };

  bf16x8 Ar[4][4];   // [ring slot][mt] -- ring-4, lookahead 3 (no aliasing)

  for (int j = 0; j < cnt; ++j) {
    const int aj = alist[j];
    const bf16_t* __restrict__ wblk = wpk + (size_t)(aj & 255) * 65536;
    const int cb = aj >> 8;

    __syncthreads();       // all waves done reading xst(j-1); vmcnt drained
    issue_x(cb);
    // A prologue: s = 0,1,2 into slots 0,1,2 (drained by the next barrier)
    #pragma unroll
    for (int s = 0; s < 3; ++s)
      #pragma unroll
      for (int mt = 0; mt < 4; ++mt)
        Ar[s][mt] = *(const bf16x8*)(wblk + (size_t)s * 2048 + (mt * 64 + lane) * 8);
    __syncthreads();       // x landed for ALL waves; A prologue landed too

    #pragma unroll
    for (int s = 0; s < 32; ++s) {
      if (s + 3 < 32) {    // prefetch A(s+3) into slot (s+3)&3
        #pragma unroll
        for (int mt = 0; mt < 4; ++mt)
          Ar[(s + 3) & 3][mt] = *(const bf16x8*)(
              wblk + (size_t)(s + 3) * 2048 + (mt * 64 + lane) * 8);
      }
      const int k  = s >> 1;                // conv tap
      const int ih = (s & 1) * 32;          // channel half
      const int ub   = wv * 64 + (lane & 15) + k + 1;
      const int scol = (ih + ((lane >> 4) & 3) * 8) ^ ((ub & 7) << 3);
      bf16x8 bfr[4];
      #pragma unroll
      for (int nt = 0; nt < 4; ++nt)
        bfr[nt] = *(const bf16x8*)(xst + (ub + nt * 16) * 64 + scol);
      #pragma unroll
      for (int mt = 0; mt < 4; ++mt)
        #pragma unroll
        for (int nt = 0; nt < 4; ++nt)
          acc[mt][nt] = __builtin_amdgcn_mfma_f32_16x16x32_bf16(
              Ar[s & 3][mt], bfr[nt], acc[mt][nt], 0, 0, 0);
    }
  }

  // ---- store (each output element exactly once; empty rows store zeros) ----
  const int mlo = ((lane >> 4) & 3) * 4, nn = lane & 15;
  #pragma unroll
  for (int mt = 0; mt < 4; ++mt) {
    #pragma unroll
    for (int nt = 0; nt < 4; ++nt) {
      const int t = t0 + wv * 64 + nt * 16 + nn;
      float* yp = y + ((size_t)n * C_LEN + (size_t)(tr * 64 + mt * 16 + mlo)) * T_LEN + t;
      #pragma unroll
      for (int r = 0; r < 4; ++r)
        yp[(size_t)r * T_LEN] = acc[mt][nt][r];
    }
  }
}

extern "C" void kernel_launch(void* const* d_in, const int* in_sizes, int n_in,
                              void* d_out, int out_size, void* d_ws, size_t ws_size,
                              hipStream_t stream) {
  const float* x   = (const float*)d_in[0];
  const float* bv  = (const float*)d_in[1];
  const int* cols  = (const int*)d_in[2];
  const int* rows  = (const int*)d_in[3];
  float* y = (float*)d_out;

  // ws layout: [wpk: 16,777,216 B][S: 33,882,112 B]  (needs ws >= 50.7 MB)
  bf16_t* wpk = (bf16_t*)d_ws;
  bf16_t* S   = (bf16_t*)((char*)d_ws + 16777216);

  prepack_kernel<<<dim3(128, 4), dim3(256), 0, stream>>>(bv, wpk);
  padzero_kernel<<<dim3(80), dim3(256), 0, stream>>>(S);
  xprep_kernel<<<dim3(32, 32, 4), dim3(256), 0, stream>>>(x, S);
  bsconv_kernel<<<dim3(8, 32, 4), dim3(256), 0, stream>>>(S, wpk, cols, rows, y);
}

// Round 11
// 177.030 us; speedup vs baseline: 2.2357x; 2.2357x over previous
//
#include <hip/hip_runtime.h>
#include <hip/hip_bf16.h>
#include <stdint.h>

typedef __bf16 bf16_t;
typedef bf16_t bf16x8 __attribute__((ext_vector_type(8)));
typedef float f32x4 __attribute__((ext_vector_type(4)));

#define T_LEN 2048
#define C_LEN 2048
#define NB 128
#define TN 256
#define SROWS 2064    // 16 zero-halo rows + 2048 data rows per batch
#define XROWS 288     // 9 x 4KB GLL rounds (256 thr); rows 0..271 consumed

// async global->LDS, 16B per lane; LDS dest = wave-uniform base + lane*16
#define GLL(gp, lp) __builtin_amdgcn_global_load_lds( \
    (const __attribute__((address_space(1))) uint32_t*)(gp), \
    (__attribute__((address_space(3))) uint32_t*)(lp), 16, 0, 0)

// ---------------------------------------------------------------------------
// Prepack weights into per-lane MFMA A-fragment layout (verified r1-r10):
// wpk[blk][s(32)][mt(4)][lane(64)][j(8)]
//   = bv[blk][o = mt*16 + (lane&15)][i = (s&1)*32 + (lane>>4)*8 + j][k = s>>1]
// ---------------------------------------------------------------------------
__global__ __launch_bounds__(256) void prepack_kernel(
    const float* __restrict__ bv, bf16_t* __restrict__ wpk)
{
  const int blk = blockIdx.x;
  const int mt  = blockIdx.y;
  const int tid = threadIdx.x;
  __shared__ float lw[16 * 64 * 17];

  const float* src = bv + (size_t)blk * 65536 + (size_t)mt * 16384;
  for (int p = 0; p < 16; ++p) {
    int idx = p * 1024 + tid * 4;
    const float4 v = *(const float4*)(src + idx);
    int o = idx >> 10;
    int i = (idx >> 4) & 63;
    int k = idx & 15;
    float* d = &lw[(o * 64 + i) * 17 + k];
    d[0] = v.x; d[1] = v.y; d[2] = v.z; d[3] = v.w;
  }
  __syncthreads();

  const int e0 = tid * 2;
  const int l  = e0 >> 3;
  const int j  = e0 & 7;
  const int o  = l & 15;
  for (int ks = 0; ks < 32; ++ks) {
    const int k  = ks >> 1;
    const int i0 = (ks & 1) * 32 + (l >> 4) * 8 + j;
    const float a = lw[(o * 64 + i0) * 17 + k];
    const float b = lw[(o * 64 + i0 + 1) * 17 + k];
    const uint16_t ba = __builtin_bit_cast(uint16_t, (bf16_t)a);
    const uint16_t bb = __builtin_bit_cast(uint16_t, (bf16_t)b);
    const uint32_t packed = (uint32_t)ba | ((uint32_t)bb << 16);
    const size_t off = ((((size_t)blk * 32 + ks) * 4 + mt) * 512) + e0;
    *(uint32_t*)(wpk + off) = packed;
  }
}

// ---------------------------------------------------------------------------
// Zero the halo rows of S.
// ---------------------------------------------------------------------------
__global__ __launch_bounds__(256) void padzero_kernel(bf16_t* __restrict__ S)
{
  const int p = blockIdx.x;  // 0..79
  const size_t g = (p < 64) ? ((size_t)(p >> 4) * SROWS + (p & 15))
                            : ((size_t)4 * SROWS + (p - 64));
  uint4 z = {0u, 0u, 0u, 0u};
  *(uint4*)(S + g * C_LEN + (size_t)threadIdx.x * 8) = z;
}

// ---------------------------------------------------------------------------
// x prepass: f32 [n][c][t] -> bf16 S[n][16+t][c'], c' = c ^ ((t&7)<<3)
// within each 64-ch block (XOR swizzle baked into global layout).
// ---------------------------------------------------------------------------
__global__ __launch_bounds__(256) void xprep_kernel(
    const float* __restrict__ x, bf16_t* __restrict__ S)
{
  const int tb = blockIdx.x, cb = blockIdx.y, n = blockIdx.z;
  const int tid = threadIdx.x;
  __shared__ float lt[64 * 67 + 4];

  #pragma unroll
  for (int p = 0; p < 4; ++p) {
    const int idx = p * 256 + tid;
    const int c   = idx >> 4;
    const int t4  = (idx & 15) * 4;
    const float4 v = *(const float4*)(
        x + ((size_t)n * C_LEN + cb * 64 + c) * T_LEN + tb * 64 + t4);
    float* d = &lt[c * 67 + t4];
    d[0] = v.x; d[1] = v.y; d[2] = v.z; d[3] = v.w;
  }
  __syncthreads();

  #pragma unroll
  for (int p = 0; p < 2; ++p) {
    const int idx = p * 256 + tid;
    const int tl  = idx >> 3;
    const int seg = idx & 7;
    const int t   = tb * 64 + tl;
    const int cbase = (seg * 8) ^ ((t & 7) << 3);
    uint32_t w[4];
    #pragma unroll
    for (int h = 0; h < 4; ++h) {
      const float a = lt[(cbase + 2 * h) * 67 + tl];
      const float b = lt[(cbase + 2 * h + 1) * 67 + tl];
      const uint16_t ba = __builtin_bit_cast(uint16_t, (bf16_t)a);
      const uint16_t bb = __builtin_bit_cast(uint16_t, (bf16_t)b);
      w[h] = (uint32_t)ba | ((uint32_t)bb << 16);
    }
    uint4 u4 = {w[0], w[1], w[2], w[3]};
    *(uint4*)(S + ((size_t)n * SROWS + 16 + t) * C_LEN + cb * 64 + seg * 8) = u4;
  }
}

// ---------------------------------------------------------------------------
// Main kernel: 256 thr (4 waves), ~78.5 KB LDS -> 2 WG/CU.
// r8 skeleton + interleaved next-phase frag reads (SGB 2-MFMA/1-DS_READ)
// with ping-pong frag registers. Counted wait at phase TAIL (r8's proven
// position) -- the cross-wave guarantee:
//   phase c tail: queue = [W(c+2),W(c+3),W(c+4)] = 6 -> vmcnt(4) forces
//   W(c+2) landed for THIS wave before barrier(c); hence at barrier(c) ALL
//   waves' W(c+2) is landed, and cluster c+1's reads of frags(c+2) are
//   race-free for every wave.  (r10's head-wait lacked exactly this.)
// Ledger: seam issues x:9+W0..W3:8, vmcnt(4) [x,W0,W1 forced]; phase c<=11
// issues W(c+4) at head; tails: c<=11 vmcnt(4), c=12 vmcnt(2), c=13
// vmcnt(0), c>=14 none. Ring slot (c+4)%5 overwrite is >=1 barrier after
// its last reader's lgkm-drain (verified for seam slots 0..4 too).
// ---------------------------------------------------------------------------
__global__ __launch_bounds__(256, 2) void bsconv_kernel(
    const bf16_t* __restrict__ S, const bf16_t* __restrict__ wpk,
    const int* __restrict__ cols, const int* __restrict__ rows,
    float* __restrict__ y)
{
  const int tt = blockIdx.x, tr = blockIdx.y, n = blockIdx.z;
  const int t0 = tt * TN;
  const int tid = threadIdx.x;
  const int lane = tid & 63, wv = tid >> 6;   // wv 0..3

  __shared__ __attribute__((aligned(16))) bf16_t xst[XROWS * 64];   // 36864 B
  __shared__ __attribute__((aligned(16))) bf16_t wring[5][4096];    // 40960 B
  __shared__ int alist[NB];                   // packed: blk | (col<<8)
  __shared__ unsigned long long wmask[2];

  // ---- build active-block list (order-preserving => deterministic) ----
  {
    const int r  = (tid < NB) ? rows[tid] : -1;
    const int cb = (tid < NB) ? cols[tid] : 0;
    const bool match = (r == tr);
    const unsigned long long m = __ballot(match);
    if (wv < 2 && lane == 0) wmask[wv] = m;
    __syncthreads();
    if (match) {
      int pos = __popcll(wmask[wv] & ((1ull << lane) - 1ull));
      if (wv == 1) pos += __popcll(wmask[0]);
      alist[pos] = tid | (cb << 8);
    }
    __syncthreads();
  }
  const int cnt = __popcll(wmask[0]) + __popcll(wmask[1]);

  f32x4 acc[4][4];
  #pragma unroll
  for (int a = 0; a < 4; ++a)
    #pragma unroll
    for (int b = 0; b < 4; ++b) {
      f32x4 z = {0.f, 0.f, 0.f, 0.f};
      acc[a][b] = z;
    }

  const size_t srow0 = (size_t)n * SROWS + t0;  // S row of LDS row u=0
  const int lxb = tid * 16;                     // lane byte within a 4KB round

  auto issue_x = [&](int cb) {                  // 9 rounds = 36 KB, single buf
    #pragma unroll
    for (int q = 0; q < 9; ++q) {
      const int lb = q * 4096 + lxb;
      const int u  = lb >> 7;                   // LDS row (128 B rows)
      const int ib = (lb >> 1) & 63;
      GLL(S + (srow0 + u) * C_LEN + cb * 64 + ib, (char*)xst + lb);
    }
  };
  auto issue_wc = [&](const bf16_t* wblk, int c, int slot) {  // 8KB chunk
    const bf16_t* wsrc = wblk + (size_t)c * 4096;
    #pragma unroll
    for (int p = 0; p < 2; ++p) {
      const int lb = p * 4096 + lxb;
      GLL(wsrc + (lb >> 1), (char*)wring[slot] + lb);
    }
  };

  // ping-pong fragment registers (named sets, statically selected)
  bf16x8 afA[2][4], bfA[2][4], afB[2][4], bfB[2][4];

  auto read_frags = [&](int c, bf16x8 (&aD)[2][4], bf16x8 (&bD)[2][4]) {
    const bf16_t* wl = wring[c % 5];
    #pragma unroll
    for (int kk = 0; kk < 2; ++kk) {
      #pragma unroll
      for (int mt = 0; mt < 4; ++mt)
        aD[kk][mt] = *(const bf16x8*)(wl + ((kk * 4 + mt) * 64 + lane) * 8);
      const int ub   = wv * 64 + (lane & 15) + c + 1;
      const int scol = (kk * 32 + ((lane >> 4) & 3) * 8) ^ ((ub & 7) << 3);
      #pragma unroll
      for (int nt = 0; nt < 4; ++nt)
        bD[kk][nt] = *(const bf16x8*)(xst + (ub + nt * 16) * 64 + scol);
    }
  };

  for (int j = 0; j < cnt; ++j) {
    const int aj = alist[j];
    const bf16_t* wblk = wpk + (size_t)(aj & 255) * 65536;
    const int cb = aj >> 8;

    // ---- seam: stage x (all prior xst reads >=1 barrier old) + W0..W3 ----
    issue_x(cb);
    issue_wc(wblk, 0, 0);
    issue_wc(wblk, 1, 1);
    issue_wc(wblk, 2, 2);
    issue_wc(wblk, 3, 3);
    asm volatile("s_waitcnt vmcnt(4)" ::: "memory");  // x,W0,W1 forced landed
    __builtin_amdgcn_s_barrier();                     // all waves: x,W0,W1 ok
    read_frags(0, afA, bfA);                          // frags(0) -> A set

    #pragma unroll
    for (int c = 0; c < 16; ++c) {
      asm volatile("s_waitcnt lgkmcnt(0)" ::: "memory");  // frags(c) in regs
      __builtin_amdgcn_sched_barrier(0);                  // rule 18 fence
      if (c <= 11) issue_wc(wblk, c + 4, (c + 4) % 5);    // head issue
      __builtin_amdgcn_s_setprio(1);

      // cluster: 32 MFMA on frags(c) + 16 ds_reads of frags(c+1), interleaved
      if ((c & 1) == 0) {
        if (c < 15) read_frags(c + 1, afB, bfB);
        #pragma unroll
        for (int kk = 0; kk < 2; ++kk)
          #pragma unroll
          for (int mt = 0; mt < 4; ++mt)
            #pragma unroll
            for (int nt = 0; nt < 4; ++nt)
              acc[mt][nt] = __builtin_amdgcn_mfma_f32_16x16x32_bf16(
                  afA[kk][mt], bfA[kk][nt], acc[mt][nt], 0, 0, 0);
      } else {
        if (c < 15) read_frags(c + 1, afA, bfA);
        #pragma unroll
        for (int kk = 0; kk < 2; ++kk)
          #pragma unroll
          for (int mt = 0; mt < 4; ++mt)
            #pragma unroll
            for (int nt = 0; nt < 4; ++nt)
              acc[mt][nt] = __builtin_amdgcn_mfma_f32_16x16x32_bf16(
                  afB[kk][mt], bfB[kk][nt], acc[mt][nt], 0, 0, 0);
      }
      if (c < 15) {
        #pragma unroll
        for (int g = 0; g < 16; ++g) {
          __builtin_amdgcn_sched_group_barrier(0x008, 2, 0);  // 2 MFMA
          __builtin_amdgcn_sched_group_barrier(0x100, 1, 0);  // 1 DS_READ
        }
      }

      __builtin_amdgcn_s_setprio(0);
      __builtin_amdgcn_sched_barrier(0);
      // ---- counted TAIL wait: forces W(c+2) landed before barrier(c) ----
      if (c <= 11)      asm volatile("s_waitcnt vmcnt(4)" ::: "memory");
      else if (c == 12) asm volatile("s_waitcnt vmcnt(2)" ::: "memory");
      else if (c == 13) asm volatile("s_waitcnt vmcnt(0)" ::: "memory");
      __builtin_amdgcn_s_barrier();
    }
  }

  // ---- store (each output element exactly once; empty rows store zeros) ----
  const int mlo = ((lane >> 4) & 3) * 4, nn = lane & 15;
  #pragma unroll
  for (int mt = 0; mt < 4; ++mt) {
    #pragma unroll
    for (int nt = 0; nt < 4; ++nt) {
      const int t = t0 + wv * 64 + nt * 16 + nn;
      float* yp = y + ((size_t)n * C_LEN + (size_t)(tr * 64 + mt * 16 + mlo)) * T_LEN + t;
      #pragma unroll
      for (int r = 0; r < 4; ++r)
        yp[(size_t)r * T_LEN] = acc[mt][nt][r];
    }
  }
}

extern "C" void kernel_launch(void* const* d_in, const int* in_sizes, int n_in,
                              void* d_out, int out_size, void* d_ws, size_t ws_size,
                              hipStream_t stream) {
  const float* x   = (const float*)d_in[0];
  const float* bv  = (const float*)d_in[1];
  const int* cols  = (const int*)d_in[2];
  const int* rows  = (const int*)d_in[3];
  float* y = (float*)d_out;

  // ws layout: [wpk: 16,777,216 B][S: 33,882,112 B]  (needs ws >= 50.7 MB)
  bf16_t* wpk = (bf16_t*)d_ws;
  bf16_t* S   = (bf16_t*)((char*)d_ws + 16777216);

  prepack_kernel<<<dim3(128, 4), dim3(256), 0, stream>>>(bv, wpk);
  padzero_kernel<<<dim3(80), dim3(256), 0, stream>>>(S);
  xprep_kernel<<<dim3(32, 32, 4), dim3(256), 0, stream>>>(x, S);
  bsconv_kernel<<<dim3(8, 32, 4), dim3(256), 0, stream>>>(S, wpk, cols, rows, y);
}